// Round 12
// baseline (206.267 us; speedup 1.0000x reference)
//
#include <hip/hip_runtime.h>
#include <hip/hip_fp16.h>
#include <math.h>

#define T_STEPS 12
#define HID 64
#define GWPB 13             // waves per block (241 blocks <= 256 CUs, all resident)
#define GBLOCK (GWPB*64)    // 832 threads
#define HSTR2 68            // h-tile row stride in f32 (64 + 4 pad)
#define B_LDS_BYTES 49152   // 48 slots x 512 fp16 (single-precision-B, fp16)
#define WG_LDS_BYTES 1792   // W_gcn(128) + b_gcn(64) + interleaved biases (256) = 448 f32
#define H_LDS_BYTES (GWPB*16*HSTR2*4)   // 56576
#define LDS_TOTAL (B_LDS_BYTES + WG_LDS_BYTES + H_LDS_BYTES)  // 107520

#define GRID_P 256          // partition blocks for radix passes A/C

typedef _Float16 half8 __attribute__((ext_vector_type(8)));
typedef __fp16   fp16x2 __attribute__((ext_vector_type(2)));   // pkrtz result type
typedef __attribute__((ext_vector_type(4))) float floatx4;

// Fast transcendentals: without -ffast-math, 1.0f/x lowers to the full IEEE
// divide sequence (~10 serially-dependent VALU ops). v_rcp_f32 is ~1ulp.
__device__ __forceinline__ float fast_sigmoid(float x){
  float e = __builtin_amdgcn_exp2f(-1.442695041f * x);
  return __builtin_amdgcn_rcpf(1.0f + e);
}
__device__ __forceinline__ float fast_tanh(float x){   // tanh(x) = 1 - 2/(1+e^{2x})
  float e = __builtin_amdgcn_exp2f(2.885390082f * x);
  return fmaf(-2.0f, __builtin_amdgcn_rcpf(1.0f + e), 1.0f);
}
// split f32 pair -> fp16 hi pair + fp16 residual pair (RTZ hi, residual near-exact)
__device__ __forceinline__ void split2(float f0, float f1, unsigned &hi, unsigned &lo){
  fp16x2 h = __builtin_amdgcn_cvt_pkrtz(f0, f1);
  float b0 = (float)h[0], b1 = (float)h[1];
  fp16x2 l = __builtin_amdgcn_cvt_pkrtz(f0 - b0, f1 - b1);
  hi = __builtin_bit_cast(unsigned, h);
  lo = __builtin_bit_cast(unsigned, l);
}

// --- CSR build via 2-level counting sort (ZERO global atomics) -----------
// 6-dispatch chain (was 8): scan2b folded into scatterC/fineD as an in-block
// LDS rescan of the <=256 block sums; xs_scale folded into fineD (which
// already computes dinv per node). Each removed stage saves a launch +
// grid drain/fill bubble + an intermediate-buffer round trip.

// Pass A: per-block LDS histogram over buckets (dst>>6); packB fused.
__global__ void histA_packB_kernel(const int* __restrict__ ei, int E, int nbkt,
                                   int* __restrict__ table,
                                   const float* __restrict__ W_ih, const float* __restrict__ W_hh,
                                   unsigned short* __restrict__ Bpk){
  __shared__ int h[1024];
  int tid = threadIdx.x;
  #pragma unroll
  for (int i = tid; i < 1024; i += 256) h[i] = 0;
  __syncthreads();
  int epb = (E + GRID_P - 1)/GRID_P;
  int e0 = blockIdx.x*epb, e1 = (e0 + epb < E) ? e0 + epb : E;
  for (int e = e0 + tid; e < e1; e += 256)
    atomicAdd(&h[ei[E + e] >> 6], 1);
  __syncthreads();
  for (int b = tid; b < nbkt; b += 256)
    table[b*GRID_P + blockIdx.x] = h[b];

  int gtid = blockIdx.x*256 + tid;
  if (gtid < 48*512){
    int q = gtid >> 9;
    int rr = gtid & 511;
    int l = rr >> 3, j = rr & 7;
    int g, c4, kt;
    if (q < 32){ g = q >> 4; int rem = q & 15; c4 = rem >> 2; kt = rem & 3; }
    else if (q < 40){ g = 2; c4 = (q-32) >> 1; kt = (q-32) & 1; }
    else            { g = 3; c4 = (q-40) >> 1; kt = ((q-40) & 1) + 2; }
    int k  = kt*32 + (l >> 4)*8 + j;
    int n  = l & 15;
    int jc = c4*16 + n;
    float w;
    if (g == 0)      w = (k < 64) ? W_ih[jc*64 + k]      : W_hh[jc*64 + (k-64)];
    else if (g == 1) w = (k < 64) ? W_ih[(64+jc)*64 + k] : W_hh[(64+jc)*64 + (k-64)];
    else if (g == 2) w = W_ih[(128+jc)*64 + k];
    else             w = W_hh[(128+jc)*64 + (k-64)];
    _Float16 hv = (_Float16)w;   // RNE
    Bpk[q*512 + l*8 + j] = __builtin_bit_cast(unsigned short, hv);
  }
}

// per-1024-block inclusive scan: wave shfl-scan + cross-wave fixup (2 barriers)
__global__ void scan1_kernel(const int* __restrict__ cnt, int* __restrict__ part,
                             int* __restrict__ bsum, int Ntot){
  __shared__ int wsum[16];
  int tid = threadIdx.x;
  int g = blockIdx.x*1024 + tid;
  int v = (g < Ntot) ? cnt[g] : 0;
  int lane = tid & 63, wv = tid >> 6;
  int s = v;
  #pragma unroll
  for (int off = 1; off < 64; off <<= 1){
    int u = __shfl_up(s, off, 64);
    if (lane >= off) s += u;
  }
  if (lane == 63) wsum[wv] = s;
  __syncthreads();
  if (wv == 0){
    int w = (lane < 16) ? wsum[lane] : 0;
    #pragma unroll
    for (int off = 1; off < 16; off <<= 1){
      int u = __shfl_up(w, off, 64);
      if (lane >= off) w += u;
    }
    if (lane < 16) wsum[lane] = w;
  }
  __syncthreads();
  int incl = (wv ? wsum[wv-1] : 0) + s;
  if (g < Ntot) part[g] = incl;
  if (tid == 1023) bsum[blockIdx.x] = incl;
}

// in-block rescan of <=256 block sums into sbincl[] (256 threads, 2 barriers)
__device__ __forceinline__ void rescan_bsum(const int* __restrict__ bsum, int nb,
                                            int* sbincl, int* ws4){
  int tid = threadIdx.x;
  int lane = tid & 63, wv = tid >> 6;
  int v = (tid < nb) ? bsum[tid] : 0;
  int s = v;
  #pragma unroll
  for (int off = 1; off < 64; off <<= 1){
    int u = __shfl_up(s, off, 64);
    if (lane >= off) s += u;
  }
  if (lane == 63) ws4[wv] = s;
  __syncthreads();
  if (wv == 0){
    int w = (lane < 4) ? ws4[lane] : 0;
    #pragma unroll
    for (int off = 1; off < 4; off <<= 1){
      int u = __shfl_up(w, off, 64);
      if (lane >= off) w += u;
    }
    if (lane < 4) ws4[lane] = w;
  }
  __syncthreads();
  sbincl[tid] = (wv ? ws4[wv-1] : 0) + s;
  __syncthreads();
}

__device__ __forceinline__ int full_incl_l(const int* __restrict__ part,
                                           const int* sbincl, int i){
  return part[i] + ((i >= 1024) ? sbincl[(i >> 10) - 1] : 0);
}

// Pass C: scatter (src,dst) pairs into bucket-sorted order via LDS cursors.
__global__ void scatterC_kernel(const int* __restrict__ ei, int E, int nbkt,
                                const int* __restrict__ table,
                                const int* __restrict__ part, const int* __restrict__ bsum,
                                int nb, int2* __restrict__ sorted){
  __shared__ int cursor[1024];
  __shared__ int sbincl[256];
  __shared__ int ws4[4];
  int tid = threadIdx.x;
  rescan_bsum(bsum, nb, sbincl, ws4);
  for (int b = tid; b < nbkt; b += 256){
    int flat = b*GRID_P + blockIdx.x;
    cursor[b] = full_incl_l(part, sbincl, flat) - table[flat];   // exclusive base
  }
  __syncthreads();
  int epb = (E + GRID_P - 1)/GRID_P;
  int e0 = blockIdx.x*epb, e1 = (e0 + epb < E) ? e0 + epb : E;
  for (int e = e0 + tid; e < e1; e += 256){
    int src = ei[e], dst = ei[E + e];
    int pos = atomicAdd(&cursor[dst >> 6], 1);
    sorted[pos] = make_int2(src, dst);
  }
}

// Pass D: per-bucket fine CSR (64 nodes): LDS count -> wave scan ->
// row_start + dinv + csr scatter + xs scaling (xs_scale fused here: the
// block owns nodes b*64..b*64+63 and already has their dinv in registers).
__global__ void fineD_kernel(const int2* __restrict__ sorted,
                             const int* __restrict__ part, const int* __restrict__ bsum,
                             int nb, int* __restrict__ row_start, float* __restrict__ dinv,
                             int* __restrict__ csr,
                             const float* __restrict__ x, float4* __restrict__ xs,
                             int N, int nbkt){
  __shared__ int fh[64];
  __shared__ int fx[64];
  __shared__ float fdv[64];
  __shared__ int sbincl[256];
  __shared__ int ws4[4];
  int tid = threadIdx.x;
  int b = blockIdx.x;
  rescan_bsum(bsum, nb, sbincl, ws4);
  int start = (b == 0) ? 0 : full_incl_l(part, sbincl, b*GRID_P - 1);
  int end   = full_incl_l(part, sbincl, (b+1)*GRID_P - 1);
  if (tid < 64) fh[tid] = 0;
  __syncthreads();
  for (int i = start + tid; i < end; i += 256)
    atomicAdd(&fh[sorted[i].y & 63], 1);
  __syncthreads();
  if (tid < 64){
    int c = fh[tid];
    int s = c;
    #pragma unroll
    for (int off = 1; off < 64; off <<= 1){
      int u = __shfl_up(s, off, 64);
      if (tid >= off) s += u;
    }
    int excl = s - c;
    fx[tid] = start + excl;          // cursor init = global row start
    float dn = rsqrtf((float)c + 1.0f);
    fdv[tid] = dn;
    int node = b*64 + tid;
    if (node < N){
      row_start[node] = start + excl;
      dinv[node] = dn;
    }
    if (b == nbkt-1 && tid == 0) row_start[N] = end;
  }
  __syncthreads();
  for (int i = start + tid; i < end; i += 256){
    int2 sd = sorted[i];
    int pos = atomicAdd(&fx[sd.y & 63], 1);
    csr[pos] = sd.x;
  }
  // fused xs scaling for this block's 64 nodes (384 float4s / 256 threads)
  for (int idx = tid; idx < 64*6; idx += 256){
    int nl = idx / 6;
    int node = b*64 + nl;
    if (node < N){
      float4 v = ((const float4*)x)[node*6 + (idx - nl*6)];
      float dn = fdv[nl];
      xs[node*6 + (idx - nl*6)] = make_float4(dn*v.x, dn*v.y, dn*v.z, dn*v.w);
    }
  }
}

// Divergence-balanced gather: TWO lanes per (node,quarter), parity-strided
// over the CSR row, combined via shfl_xor(1).
__global__ void gather6_kernel(const float4* __restrict__ xs, const int* __restrict__ row_start,
                               const int* __restrict__ csr, const float* __restrict__ dinv,
                               float4* __restrict__ rin, int N){
  int tid = blockIdx.x*blockDim.x + threadIdx.x;
  if (tid >= N*12) return;
  int pq  = tid >> 1;        // (node, quarter) index
  int par = tid & 1;
  int n = pq / 6;
  int q = pq - n*6;
  int s0 = row_start[n], s1 = row_start[n+1];
  float4 acc = make_float4(0.f, 0.f, 0.f, 0.f);
  int e = s0 + par;
  for (; e + 2 < s1; e += 4){
    float4 va = xs[csr[e]*6 + q];
    float4 vb = xs[csr[e+2]*6 + q];
    acc.x += va.x + vb.x;
    acc.y += va.y + vb.y;
    acc.z += va.z + vb.z;
    acc.w += va.w + vb.w;
  }
  if (e < s1){
    float4 va = xs[csr[e]*6 + q];
    acc.x += va.x; acc.y += va.y; acc.z += va.z; acc.w += va.w;
  }
  acc.x += __shfl_xor(acc.x, 1, 64);
  acc.y += __shfl_xor(acc.y, 1, 64);
  acc.z += __shfl_xor(acc.z, 1, 64);
  acc.w += __shfl_xor(acc.w, 1, 64);
  if (par == 0){
    float4 self = xs[n*6 + q];
    float dn = dinv[n];
    rin[pq] = make_float4(dn*(acc.x + self.x), dn*(acc.y + self.y),
                          dn*(acc.z + self.z), dn*(acc.w + self.w));
  }
}

// Fused 12-step GRU + FC via fp16 2-term MFMA (Ahi*B + Alo*B; B single fp16).
// PROVEN round-8/9 core (90.9us): wave-private 16-node tiles, NO barriers in
// the t-loop, f32 h-tile, unroll-2 c4, 13 waves/block, 241 blocks.
__global__ __attribute__((amdgpu_waves_per_eu(1, 4))) __launch_bounds__(GBLOCK)
void gru16_kernel(const float* __restrict__ rin,
                  const float* __restrict__ W_gcn, const float* __restrict__ b_gcn,
                  const unsigned short* __restrict__ Bpk,
                  const float* __restrict__ b_ih, const float* __restrict__ b_hh,
                  const float* __restrict__ W_fc, const float* __restrict__ b_fc,
                  float* __restrict__ out, int N, int ntiles){
  extern __shared__ char smem[];
  unsigned short* Bl = (unsigned short*)smem;
  float*    wgl = (float*)(smem + B_LDS_BYTES);
  float*    hl  = (float*)(smem + B_LDS_BYTES + WG_LDS_BYTES);

  {
    const int4* Bg = (const int4*)Bpk;
    int4* Bd = (int4*)smem;
    for (int i = threadIdx.x; i < 3072; i += GBLOCK) Bd[i] = Bg[i];
    if (threadIdx.x < 64){
      int l = threadIdx.x;
      wgl[l]       = W_gcn[l];
      wgl[64 + l]  = W_gcn[64 + l];
      wgl[128 + l] = b_gcn[l];
      // interleaved per-channel biases: one b128 read per c4 in the hot loop
      wgl[192 + 4*l + 0] = b_ih[l]       + b_hh[l];        // bR
      wgl[192 + 4*l + 1] = b_ih[64 + l]  + b_hh[64 + l];   // bZ
      wgl[192 + 4*l + 2] = b_ih[128 + l];                  // bNi
      wgl[192 + 4*l + 3] = b_hh[128 + l];                  // bNh
    }
  }
  __syncthreads();

  int lane = threadIdx.x & 63;
  int wid  = threadIdx.x >> 6;
  int tile = blockIdx.x*GWPB + wid;
  if (tile >= ntiles) return;
  int n0   = tile << 4;
  int quad = lane >> 4;
  int n16  = lane & 15;
  float* hwp = hl + wid*(16*HSTR2);

  for (int i = lane; i < 16*HSTR2; i += 64) hwp[i] = 0.f;   // wave-private, no barrier

  float wfc = W_fc[lane], bfc = b_fc[0];

  int nn = n0 + n16; if (nn > N-1) nn = N-1;
  const float* rbase = rin + (size_t)nn*24;
  float2 rcur = *(const float2*)rbase;

  #pragma unroll 1
  for (int t = 0; t < T_STEPS; ++t){
    float2 rnx = (t < T_STEPS-1) ? *(const float2*)(rbase + 2*(t+1)) : rcur;

    half8 ahi[4], alo[4];
    // s half (kt 0,1): compute in A-frag layout from wgl, fp16 split
    #pragma unroll
    for (int kt = 0; kt < 2; ++kt){
      int j0 = kt*32 + quad*8;
      floatx4 g0a = *(floatx4*)&wgl[j0],       g0b = *(floatx4*)&wgl[j0+4];
      floatx4 g1a = *(floatx4*)&wgl[64 + j0],  g1b = *(floatx4*)&wgl[64 + j0+4];
      floatx4 bga = *(floatx4*)&wgl[128 + j0], bgb = *(floatx4*)&wgl[128 + j0+4];
      float f[8];
      #pragma unroll
      for (int j = 0; j < 4; ++j){
        f[j]   = fmaxf(fmaf(rcur.x, g0a[j], fmaf(rcur.y, g1a[j], bga[j])), 0.f);
        f[4+j] = fmaxf(fmaf(rcur.x, g0b[j], fmaf(rcur.y, g1b[j], bgb[j])), 0.f);
      }
      union { half8 v; unsigned w[4]; } H, L;
      #pragma unroll
      for (int p2 = 0; p2 < 4; ++p2)
        split2(f[2*p2], f[2*p2+1], H.w[p2], L.w[p2]);
      ahi[kt] = H.v; alo[kt] = L.v;
    }
    // h half (kt 2,3): f32 h from LDS, same split2 as s-half
    #pragma unroll
    for (int kt = 2; kt < 4; ++kt){
      int base = n16*HSTR2 + (kt-2)*32 + quad*8;
      floatx4 fa = *(const floatx4*)&hwp[base];
      floatx4 fb = *(const floatx4*)&hwp[base+4];
      union { half8 v; unsigned w[4]; } H, L;
      split2(fa[0], fa[1], H.w[0], L.w[0]);
      split2(fa[2], fa[3], H.w[1], L.w[1]);
      split2(fb[0], fb[1], H.w[2], L.w[2]);
      split2(fb[2], fb[3], H.w[3], L.w[3]);
      ahi[kt] = H.v; alo[kt] = L.v;
    }

    // unroll-2: two gate-groups in flight (epilogue ∥ next LDS/MFMA).
    #pragma unroll 2
    for (int c4 = 0; c4 < 4; ++c4){
      int jc = (c4<<4) + n16;
      floatx4 bv = *(floatx4*)&wgl[192 + 4*jc];     // bR,bZ,bNi,bNh in one b128
      // hprev prefetch: issue LDS reads before the MFMA cluster so their
      // latency hides under the 24 MFMAs instead of the epilogue chain.
      float hpw[4];
      #pragma unroll
      for (int r = 0; r < 4; ++r)
        hpw[r] = hwp[(quad*4 + r)*HSTR2 + (c4<<4) + n16];
      floatx4 aR = (floatx4){bv[0], bv[0], bv[0], bv[0]};
      floatx4 aZ = (floatx4){bv[1], bv[1], bv[1], bv[1]};
      floatx4 aN = (floatx4){bv[2], bv[2], bv[2], bv[2]};
      floatx4 aH = (floatx4){bv[3], bv[3], bv[3], bv[3]};
      #pragma unroll
      for (int kt = 0; kt < 4; ++kt){
        int qr = (c4<<2) + kt;
        half8 wR = *(const half8*)&Bl[qr*512 + lane*8];
        aR = __builtin_amdgcn_mfma_f32_16x16x32_f16(ahi[kt], wR, aR, 0,0,0);
        aR = __builtin_amdgcn_mfma_f32_16x16x32_f16(alo[kt], wR, aR, 0,0,0);
        int qz = 16 + (c4<<2) + kt;
        half8 wZ = *(const half8*)&Bl[qz*512 + lane*8];
        aZ = __builtin_amdgcn_mfma_f32_16x16x32_f16(ahi[kt], wZ, aZ, 0,0,0);
        aZ = __builtin_amdgcn_mfma_f32_16x16x32_f16(alo[kt], wZ, aZ, 0,0,0);
        if (kt < 2){
          int qn = 32 + (c4<<1) + kt;
          half8 wN = *(const half8*)&Bl[qn*512 + lane*8];
          aN = __builtin_amdgcn_mfma_f32_16x16x32_f16(ahi[kt], wN, aN, 0,0,0);
          aN = __builtin_amdgcn_mfma_f32_16x16x32_f16(alo[kt], wN, aN, 0,0,0);
        } else {
          int qh = 40 + (c4<<1) + (kt-2);
          half8 wH = *(const half8*)&Bl[qh*512 + lane*8];
          aH = __builtin_amdgcn_mfma_f32_16x16x32_f16(ahi[kt], wH, aH, 0,0,0);
          aH = __builtin_amdgcn_mfma_f32_16x16x32_f16(alo[kt], wH, aH, 0,0,0);
        }
      }
      // epilogue: C/D row = quad*4+r, col = c4*16+n16; h stored as plain f32
      #pragma unroll
      for (int r = 0; r < 4; ++r){
        float hprev = hpw[r];
        float rg = fast_sigmoid(aR[r]);
        float zg = fast_sigmoid(aZ[r]);
        float ng = fast_tanh(fmaf(rg, aH[r], aN[r]));
        float hn = fmaf(zg, hprev - ng, ng);
        hwp[(quad*4 + r)*HSTR2 + (c4<<4) + n16] = hn;
      }
    }
    rcur = rnx;
  }

  // FC epilogue: h already f32
  #pragma unroll 1
  for (int m = 0; m < 16; ++m){
    float hv = hwp[m*HSTR2 + lane];
    float v = hv * wfc;
    #pragma unroll
    for (int off = 32; off >= 1; off >>= 1) v += __shfl_xor(v, off, 64);
    int n = n0 + m;
    if (lane == 0 && n < N) out[n] = v + bfc;
  }
}

extern "C" void kernel_launch(void* const* d_in, const int* in_sizes, int n_in,
                              void* d_out, int out_size, void* d_ws, size_t ws_size,
                              hipStream_t stream){
  const float* x     = (const float*)d_in[0];
  const int*   ei    = (const int*)d_in[1];
  const float* W_gcn = (const float*)d_in[2];
  const float* b_gcn = (const float*)d_in[3];
  const float* W_ih  = (const float*)d_in[4];
  const float* W_hh  = (const float*)d_in[5];
  const float* b_ih  = (const float*)d_in[6];
  const float* b_hh  = (const float*)d_in[7];
  const float* W_fc  = (const float*)d_in[8];
  const float* b_fc  = (const float*)d_in[9];
  float* out = (float*)d_out;
  const int N = in_sizes[0] / (T_STEPS*2);
  const int E = in_sizes[1] / 2;
  const int NBKT = (N + 63) >> 6;                 // 782 buckets of 64 nodes
  const int FLAT = NBKT * GRID_P;                 // 200192 table cells
  const int NB1024 = (FLAT + 1023) / 1024;        // 196 scan blocks (<=256)

  char* p = (char*)d_ws;
  auto alloc = [&](size_t bytes)->char*{
    char* r = p; p += (bytes + 255) & ~(size_t)255; return r;
  };
  int*   table     = (int*)  alloc((size_t)FLAT*4);
  int*   part      = (int*)  alloc((size_t)FLAT*4);
  int*   bsum      = (int*)  alloc((size_t)NB1024*4);
  int2*  sorted    = (int2*) alloc((size_t)E*8);
  int*   row_start = (int*)  alloc((size_t)(N+1)*4);
  int*   csr       = (int*)  alloc((size_t)E*4);
  float* dinv      = (float*)alloc((size_t)N*4);
  float* rin       = (float*)alloc((size_t)N*24*4);
  float* xs        = (float*)alloc((size_t)N*24*4);
  unsigned short* Bpk = (unsigned short*)alloc((size_t)24576*2);

  histA_packB_kernel<<<GRID_P, 256, 0, stream>>>(ei, E, NBKT, table, W_ih, W_hh, Bpk);
  scan1_kernel<<<NB1024, 1024, 0, stream>>>(table, part, bsum, FLAT);
  scatterC_kernel<<<GRID_P, 256, 0, stream>>>(ei, E, NBKT, table, part, bsum, NB1024, sorted);
  fineD_kernel<<<NBKT, 256, 0, stream>>>(sorted, part, bsum, NB1024, row_start, dinv, csr,
                                         x, (float4*)xs, N, NBKT);
  gather6_kernel<<<(N*12+255)/256, 256, 0, stream>>>((const float4*)xs, row_start, csr,
                                                     dinv, (float4*)rin, N);

  (void)hipFuncSetAttribute((const void*)gru16_kernel,
                            hipFuncAttributeMaxDynamicSharedMemorySize, LDS_TOTAL);
  int ntiles = (N + 15) / 16;                      // 3125
  int blocks = (ntiles + GWPB - 1) / GWPB;         // 241
  gru16_kernel<<<blocks, GBLOCK, LDS_TOTAL, stream>>>(rin, W_gcn, b_gcn, Bpk,
                                                      b_ih, b_hh, W_fc, b_fc,
                                                      out, N, ntiles);
}

// Round 13
// 196.435 us; speedup vs baseline: 1.0501x; 1.0501x over previous
//
#include <hip/hip_runtime.h>
#include <hip/hip_fp16.h>
#include <math.h>

#define T_STEPS 12
#define HID 64
#define GWPB 13             // waves per block (241 blocks <= 256 CUs, all resident)
#define GBLOCK (GWPB*64)    // 832 threads
#define HSTR2 68            // h-tile row stride in f32 (64 + 4 pad)
#define B_LDS_BYTES 49152   // 48 slots x 512 fp16 (single-precision-B, fp16)
#define WG_LDS_BYTES 1792   // W_gcn(128) + b_gcn(64) + interleaved biases (256) = 448 f32
#define H_LDS_BYTES (GWPB*16*HSTR2*4)   // 56576
#define LDS_TOTAL (B_LDS_BYTES + WG_LDS_BYTES + H_LDS_BYTES)  // 107520

#define GRID_P 256          // partition blocks for radix passes A/C
#define ABLK 1024           // threads/block for A and C: 16 waves/CU (was 4 -> 1/SIMD, latency-starved)

typedef _Float16 half8 __attribute__((ext_vector_type(8)));
typedef __fp16   fp16x2 __attribute__((ext_vector_type(2)));   // pkrtz result type
typedef __attribute__((ext_vector_type(4))) float floatx4;

// Fast transcendentals: without -ffast-math, 1.0f/x lowers to the full IEEE
// divide sequence (~10 serially-dependent VALU ops). v_rcp_f32 is ~1ulp.
__device__ __forceinline__ float fast_sigmoid(float x){
  float e = __builtin_amdgcn_exp2f(-1.442695041f * x);
  return __builtin_amdgcn_rcpf(1.0f + e);
}
__device__ __forceinline__ float fast_tanh(float x){   // tanh(x) = 1 - 2/(1+e^{2x})
  float e = __builtin_amdgcn_exp2f(2.885390082f * x);
  return fmaf(-2.0f, __builtin_amdgcn_rcpf(1.0f + e), 1.0f);
}
// split f32 pair -> fp16 hi pair + fp16 residual pair (RTZ hi, residual near-exact)
__device__ __forceinline__ void split2(float f0, float f1, unsigned &hi, unsigned &lo){
  fp16x2 h = __builtin_amdgcn_cvt_pkrtz(f0, f1);
  float b0 = (float)h[0], b1 = (float)h[1];
  fp16x2 l = __builtin_amdgcn_cvt_pkrtz(f0 - b0, f1 - b1);
  hi = __builtin_bit_cast(unsigned, h);
  lo = __builtin_bit_cast(unsigned, l);
}

// --- CSR build via 2-level counting sort (ZERO global atomics) -----------
// THIS ROUND: histA/scatterC blocks widened 256->1024 threads (same GRID_P
// partitioning). At 256 threads they ran 1 block/CU = 1 wave/SIMD — a
// latency-chain kernel (ei load -> LDS atomic -> random global write) with
// zero TLP to hide ~300-900cy stalls. 1024 threads = 4 waves/SIMD.
// Also: sorted[] packed to u32 (src:26b | dst&63:6b) — halves scatter write
// + fineD re-read traffic.

// Pass A: per-block LDS histogram over buckets (dst>>6); packB fused.
__global__ void histA_packB_kernel(const int* __restrict__ ei, int E, int nbkt,
                                   int* __restrict__ table,
                                   const float* __restrict__ W_ih, const float* __restrict__ W_hh,
                                   unsigned short* __restrict__ Bpk){
  __shared__ int h[1024];
  int tid = threadIdx.x;
  h[tid] = 0;
  __syncthreads();
  int epb = (E + GRID_P - 1)/GRID_P;
  int e0 = blockIdx.x*epb, e1 = (e0 + epb < E) ? e0 + epb : E;
  for (int e = e0 + tid; e < e1; e += ABLK)
    atomicAdd(&h[ei[E + e] >> 6], 1);
  __syncthreads();
  for (int b = tid; b < nbkt; b += ABLK)
    table[b*GRID_P + blockIdx.x] = h[b];

  int gtid = blockIdx.x*ABLK + tid;
  if (gtid < 48*512){
    int q = gtid >> 9;
    int rr = gtid & 511;
    int l = rr >> 3, j = rr & 7;
    int g, c4, kt;
    if (q < 32){ g = q >> 4; int rem = q & 15; c4 = rem >> 2; kt = rem & 3; }
    else if (q < 40){ g = 2; c4 = (q-32) >> 1; kt = (q-32) & 1; }
    else            { g = 3; c4 = (q-40) >> 1; kt = ((q-40) & 1) + 2; }
    int k  = kt*32 + (l >> 4)*8 + j;
    int n  = l & 15;
    int jc = c4*16 + n;
    float w;
    if (g == 0)      w = (k < 64) ? W_ih[jc*64 + k]      : W_hh[jc*64 + (k-64)];
    else if (g == 1) w = (k < 64) ? W_ih[(64+jc)*64 + k] : W_hh[(64+jc)*64 + (k-64)];
    else if (g == 2) w = W_ih[(128+jc)*64 + k];
    else             w = W_hh[(128+jc)*64 + (k-64)];
    _Float16 hv = (_Float16)w;   // RNE
    Bpk[q*512 + l*8 + j] = __builtin_bit_cast(unsigned short, hv);
  }
}

// per-1024-block inclusive scan: wave shfl-scan + cross-wave fixup (2 barriers)
__global__ void scan1_kernel(const int* __restrict__ cnt, int* __restrict__ part,
                             int* __restrict__ bsum, int Ntot){
  __shared__ int wsum[16];
  int tid = threadIdx.x;
  int g = blockIdx.x*1024 + tid;
  int v = (g < Ntot) ? cnt[g] : 0;
  int lane = tid & 63, wv = tid >> 6;
  int s = v;
  #pragma unroll
  for (int off = 1; off < 64; off <<= 1){
    int u = __shfl_up(s, off, 64);
    if (lane >= off) s += u;
  }
  if (lane == 63) wsum[wv] = s;
  __syncthreads();
  if (wv == 0){
    int w = (lane < 16) ? wsum[lane] : 0;
    #pragma unroll
    for (int off = 1; off < 16; off <<= 1){
      int u = __shfl_up(w, off, 64);
      if (lane >= off) w += u;
    }
    if (lane < 16) wsum[lane] = w;
  }
  __syncthreads();
  int incl = (wv ? wsum[wv-1] : 0) + s;
  if (g < Ntot) part[g] = incl;
  if (tid == 1023) bsum[blockIdx.x] = incl;
}

// in-block rescan of <=256 block sums into sbincl[] — 256-thread blocks
__device__ __forceinline__ void rescan_bsum(const int* __restrict__ bsum, int nb,
                                            int* sbincl, int* ws4){
  int tid = threadIdx.x;
  int lane = tid & 63, wv = tid >> 6;
  int v = (tid < nb) ? bsum[tid] : 0;
  int s = v;
  #pragma unroll
  for (int off = 1; off < 64; off <<= 1){
    int u = __shfl_up(s, off, 64);
    if (lane >= off) s += u;
  }
  if (lane == 63) ws4[wv] = s;
  __syncthreads();
  if (wv == 0){
    int w = (lane < 4) ? ws4[lane] : 0;
    #pragma unroll
    for (int off = 1; off < 4; off <<= 1){
      int u = __shfl_up(w, off, 64);
      if (lane >= off) w += u;
    }
    if (lane < 4) ws4[lane] = w;
  }
  __syncthreads();
  sbincl[tid] = (wv ? ws4[wv-1] : 0) + s;
  __syncthreads();
}

// barrier-safe variant for 1024-thread blocks: waves 0-3 do the scan work,
// all 16 waves hit every __syncthreads.
__device__ __forceinline__ void rescan_bsum_1024(const int* __restrict__ bsum, int nb,
                                                 int* sbincl, int* ws4){
  int tid = threadIdx.x;
  int lane = tid & 63, wv = tid >> 6;
  int s = 0;
  if (wv < 4){
    int v = (tid < nb) ? bsum[tid] : 0;
    s = v;
    #pragma unroll
    for (int off = 1; off < 64; off <<= 1){
      int u = __shfl_up(s, off, 64);
      if (lane >= off) s += u;
    }
    if (lane == 63) ws4[wv] = s;
  }
  __syncthreads();
  if (wv == 0){
    int w = (lane < 4) ? ws4[lane] : 0;
    #pragma unroll
    for (int off = 1; off < 4; off <<= 1){
      int u = __shfl_up(w, off, 64);
      if (lane >= off) w += u;
    }
    if (lane < 4) ws4[lane] = w;
  }
  __syncthreads();
  if (wv < 4) sbincl[tid] = (wv ? ws4[wv-1] : 0) + s;
  __syncthreads();
}

__device__ __forceinline__ int full_incl_l(const int* __restrict__ part,
                                           const int* sbincl, int i){
  return part[i] + ((i >= 1024) ? sbincl[(i >> 10) - 1] : 0);
}

// Pass C: scatter packed (src | d6<<26) into bucket-sorted order, LDS cursors.
__global__ void scatterC_kernel(const int* __restrict__ ei, int E, int nbkt,
                                const int* __restrict__ table,
                                const int* __restrict__ part, const int* __restrict__ bsum,
                                int nb, unsigned* __restrict__ sorted){
  __shared__ int cursor[1024];
  __shared__ int sbincl[256];
  __shared__ int ws4[4];
  int tid = threadIdx.x;
  rescan_bsum_1024(bsum, nb, sbincl, ws4);
  for (int b = tid; b < nbkt; b += ABLK){
    int flat = b*GRID_P + blockIdx.x;
    cursor[b] = full_incl_l(part, sbincl, flat) - table[flat];   // exclusive base
  }
  __syncthreads();
  int epb = (E + GRID_P - 1)/GRID_P;
  int e0 = blockIdx.x*epb, e1 = (e0 + epb < E) ? e0 + epb : E;
  for (int e = e0 + tid; e < e1; e += ABLK){
    unsigned src = (unsigned)ei[e];
    int dst = ei[E + e];
    int pos = atomicAdd(&cursor[dst >> 6], 1);
    sorted[pos] = src | ((unsigned)(dst & 63) << 26);
  }
}

// Pass D: per-bucket fine CSR (64 nodes): LDS count -> wave scan ->
// row_start + dinv + csr scatter + fused xs scaling.
__global__ void fineD_kernel(const unsigned* __restrict__ sorted,
                             const int* __restrict__ part, const int* __restrict__ bsum,
                             int nb, int* __restrict__ row_start, float* __restrict__ dinv,
                             int* __restrict__ csr,
                             const float* __restrict__ x, float4* __restrict__ xs,
                             int N, int nbkt){
  __shared__ int fh[64];
  __shared__ int fx[64];
  __shared__ float fdv[64];
  __shared__ int sbincl[256];
  __shared__ int ws4[4];
  int tid = threadIdx.x;
  int b = blockIdx.x;
  rescan_bsum(bsum, nb, sbincl, ws4);
  int start = (b == 0) ? 0 : full_incl_l(part, sbincl, b*GRID_P - 1);
  int end   = full_incl_l(part, sbincl, (b+1)*GRID_P - 1);
  if (tid < 64) fh[tid] = 0;
  __syncthreads();
  for (int i = start + tid; i < end; i += 256)
    atomicAdd(&fh[sorted[i] >> 26], 1);
  __syncthreads();
  if (tid < 64){
    int c = fh[tid];
    int s = c;
    #pragma unroll
    for (int off = 1; off < 64; off <<= 1){
      int u = __shfl_up(s, off, 64);
      if (tid >= off) s += u;
    }
    int excl = s - c;
    fx[tid] = start + excl;          // cursor init = global row start
    float dn = rsqrtf((float)c + 1.0f);
    fdv[tid] = dn;
    int node = b*64 + tid;
    if (node < N){
      row_start[node] = start + excl;
      dinv[node] = dn;
    }
    if (b == nbkt-1 && tid == 0) row_start[N] = end;
  }
  __syncthreads();
  for (int i = start + tid; i < end; i += 256){
    unsigned v = sorted[i];
    int pos = atomicAdd(&fx[v >> 26], 1);
    csr[pos] = (int)(v & 0x03FFFFFFu);
  }
  // fused xs scaling for this block's 64 nodes (384 float4s / 256 threads)
  for (int idx = tid; idx < 64*6; idx += 256){
    int nl = idx / 6;
    int node = b*64 + nl;
    if (node < N){
      float4 v = ((const float4*)x)[node*6 + (idx - nl*6)];
      float dn = fdv[nl];
      xs[node*6 + (idx - nl*6)] = make_float4(dn*v.x, dn*v.y, dn*v.z, dn*v.w);
    }
  }
}

// Divergence-balanced gather: TWO lanes per (node,quarter), parity-strided
// over the CSR row, combined via shfl_xor(1).
__global__ void gather6_kernel(const float4* __restrict__ xs, const int* __restrict__ row_start,
                               const int* __restrict__ csr, const float* __restrict__ dinv,
                               float4* __restrict__ rin, int N){
  int tid = blockIdx.x*blockDim.x + threadIdx.x;
  if (tid >= N*12) return;
  int pq  = tid >> 1;        // (node, quarter) index
  int par = tid & 1;
  int n = pq / 6;
  int q = pq - n*6;
  int s0 = row_start[n], s1 = row_start[n+1];
  float4 acc = make_float4(0.f, 0.f, 0.f, 0.f);
  int e = s0 + par;
  for (; e + 2 < s1; e += 4){
    float4 va = xs[csr[e]*6 + q];
    float4 vb = xs[csr[e+2]*6 + q];
    acc.x += va.x + vb.x;
    acc.y += va.y + vb.y;
    acc.z += va.z + vb.z;
    acc.w += va.w + vb.w;
  }
  if (e < s1){
    float4 va = xs[csr[e]*6 + q];
    acc.x += va.x; acc.y += va.y; acc.z += va.z; acc.w += va.w;
  }
  acc.x += __shfl_xor(acc.x, 1, 64);
  acc.y += __shfl_xor(acc.y, 1, 64);
  acc.z += __shfl_xor(acc.z, 1, 64);
  acc.w += __shfl_xor(acc.w, 1, 64);
  if (par == 0){
    float4 self = xs[n*6 + q];
    float dn = dinv[n];
    rin[pq] = make_float4(dn*(acc.x + self.x), dn*(acc.y + self.y),
                          dn*(acc.z + self.z), dn*(acc.w + self.w));
  }
}

// Fused 12-step GRU + FC via fp16 2-term MFMA (Ahi*B + Alo*B; B single fp16).
// PROVEN round-8/9 core (90.9us): wave-private 16-node tiles, NO barriers in
// the t-loop, f32 h-tile, unroll-2 c4, 13 waves/block, 241 blocks.
__global__ __attribute__((amdgpu_waves_per_eu(1, 4))) __launch_bounds__(GBLOCK)
void gru16_kernel(const float* __restrict__ rin,
                  const float* __restrict__ W_gcn, const float* __restrict__ b_gcn,
                  const unsigned short* __restrict__ Bpk,
                  const float* __restrict__ b_ih, const float* __restrict__ b_hh,
                  const float* __restrict__ W_fc, const float* __restrict__ b_fc,
                  float* __restrict__ out, int N, int ntiles){
  extern __shared__ char smem[];
  unsigned short* Bl = (unsigned short*)smem;
  float*    wgl = (float*)(smem + B_LDS_BYTES);
  float*    hl  = (float*)(smem + B_LDS_BYTES + WG_LDS_BYTES);

  {
    const int4* Bg = (const int4*)Bpk;
    int4* Bd = (int4*)smem;
    for (int i = threadIdx.x; i < 3072; i += GBLOCK) Bd[i] = Bg[i];
    if (threadIdx.x < 64){
      int l = threadIdx.x;
      wgl[l]       = W_gcn[l];
      wgl[64 + l]  = W_gcn[64 + l];
      wgl[128 + l] = b_gcn[l];
      // interleaved per-channel biases: one b128 read per c4 in the hot loop
      wgl[192 + 4*l + 0] = b_ih[l]       + b_hh[l];        // bR
      wgl[192 + 4*l + 1] = b_ih[64 + l]  + b_hh[64 + l];   // bZ
      wgl[192 + 4*l + 2] = b_ih[128 + l];                  // bNi
      wgl[192 + 4*l + 3] = b_hh[128 + l];                  // bNh
    }
  }
  __syncthreads();

  int lane = threadIdx.x & 63;
  int wid  = threadIdx.x >> 6;
  int tile = blockIdx.x*GWPB + wid;
  if (tile >= ntiles) return;
  int n0   = tile << 4;
  int quad = lane >> 4;
  int n16  = lane & 15;
  float* hwp = hl + wid*(16*HSTR2);

  for (int i = lane; i < 16*HSTR2; i += 64) hwp[i] = 0.f;   // wave-private, no barrier

  float wfc = W_fc[lane], bfc = b_fc[0];

  int nn = n0 + n16; if (nn > N-1) nn = N-1;
  const float* rbase = rin + (size_t)nn*24;
  float2 rcur = *(const float2*)rbase;

  #pragma unroll 1
  for (int t = 0; t < T_STEPS; ++t){
    float2 rnx = (t < T_STEPS-1) ? *(const float2*)(rbase + 2*(t+1)) : rcur;

    half8 ahi[4], alo[4];
    // s half (kt 0,1): compute in A-frag layout from wgl, fp16 split
    #pragma unroll
    for (int kt = 0; kt < 2; ++kt){
      int j0 = kt*32 + quad*8;
      floatx4 g0a = *(floatx4*)&wgl[j0],       g0b = *(floatx4*)&wgl[j0+4];
      floatx4 g1a = *(floatx4*)&wgl[64 + j0],  g1b = *(floatx4*)&wgl[64 + j0+4];
      floatx4 bga = *(floatx4*)&wgl[128 + j0], bgb = *(floatx4*)&wgl[128 + j0+4];
      float f[8];
      #pragma unroll
      for (int j = 0; j < 4; ++j){
        f[j]   = fmaxf(fmaf(rcur.x, g0a[j], fmaf(rcur.y, g1a[j], bga[j])), 0.f);
        f[4+j] = fmaxf(fmaf(rcur.x, g0b[j], fmaf(rcur.y, g1b[j], bgb[j])), 0.f);
      }
      union { half8 v; unsigned w[4]; } H, L;
      #pragma unroll
      for (int p2 = 0; p2 < 4; ++p2)
        split2(f[2*p2], f[2*p2+1], H.w[p2], L.w[p2]);
      ahi[kt] = H.v; alo[kt] = L.v;
    }
    // h half (kt 2,3): f32 h from LDS, same split2 as s-half
    #pragma unroll
    for (int kt = 2; kt < 4; ++kt){
      int base = n16*HSTR2 + (kt-2)*32 + quad*8;
      floatx4 fa = *(const floatx4*)&hwp[base];
      floatx4 fb = *(const floatx4*)&hwp[base+4];
      union { half8 v; unsigned w[4]; } H, L;
      split2(fa[0], fa[1], H.w[0], L.w[0]);
      split2(fa[2], fa[3], H.w[1], L.w[1]);
      split2(fb[0], fb[1], H.w[2], L.w[2]);
      split2(fb[2], fb[3], H.w[3], L.w[3]);
      ahi[kt] = H.v; alo[kt] = L.v;
    }

    // unroll-2: two gate-groups in flight (epilogue ∥ next LDS/MFMA).
    #pragma unroll 2
    for (int c4 = 0; c4 < 4; ++c4){
      int jc = (c4<<4) + n16;
      floatx4 bv = *(floatx4*)&wgl[192 + 4*jc];     // bR,bZ,bNi,bNh in one b128
      // hprev prefetch: issue LDS reads before the MFMA cluster so their
      // latency hides under the 24 MFMAs instead of the epilogue chain.
      float hpw[4];
      #pragma unroll
      for (int r = 0; r < 4; ++r)
        hpw[r] = hwp[(quad*4 + r)*HSTR2 + (c4<<4) + n16];
      floatx4 aR = (floatx4){bv[0], bv[0], bv[0], bv[0]};
      floatx4 aZ = (floatx4){bv[1], bv[1], bv[1], bv[1]};
      floatx4 aN = (floatx4){bv[2], bv[2], bv[2], bv[2]};
      floatx4 aH = (floatx4){bv[3], bv[3], bv[3], bv[3]};
      #pragma unroll
      for (int kt = 0; kt < 4; ++kt){
        int qr = (c4<<2) + kt;
        half8 wR = *(const half8*)&Bl[qr*512 + lane*8];
        aR = __builtin_amdgcn_mfma_f32_16x16x32_f16(ahi[kt], wR, aR, 0,0,0);
        aR = __builtin_amdgcn_mfma_f32_16x16x32_f16(alo[kt], wR, aR, 0,0,0);
        int qz = 16 + (c4<<2) + kt;
        half8 wZ = *(const half8*)&Bl[qz*512 + lane*8];
        aZ = __builtin_amdgcn_mfma_f32_16x16x32_f16(ahi[kt], wZ, aZ, 0,0,0);
        aZ = __builtin_amdgcn_mfma_f32_16x16x32_f16(alo[kt], wZ, aZ, 0,0,0);
        if (kt < 2){
          int qn = 32 + (c4<<1) + kt;
          half8 wN = *(const half8*)&Bl[qn*512 + lane*8];
          aN = __builtin_amdgcn_mfma_f32_16x16x32_f16(ahi[kt], wN, aN, 0,0,0);
          aN = __builtin_amdgcn_mfma_f32_16x16x32_f16(alo[kt], wN, aN, 0,0,0);
        } else {
          int qh = 40 + (c4<<1) + (kt-2);
          half8 wH = *(const half8*)&Bl[qh*512 + lane*8];
          aH = __builtin_amdgcn_mfma_f32_16x16x32_f16(ahi[kt], wH, aH, 0,0,0);
          aH = __builtin_amdgcn_mfma_f32_16x16x32_f16(alo[kt], wH, aH, 0,0,0);
        }
      }
      // epilogue: C/D row = quad*4+r, col = c4*16+n16; h stored as plain f32
      #pragma unroll
      for (int r = 0; r < 4; ++r){
        float hprev = hpw[r];
        float rg = fast_sigmoid(aR[r]);
        float zg = fast_sigmoid(aZ[r]);
        float ng = fast_tanh(fmaf(rg, aH[r], aN[r]));
        float hn = fmaf(zg, hprev - ng, ng);
        hwp[(quad*4 + r)*HSTR2 + (c4<<4) + n16] = hn;
      }
    }
    rcur = rnx;
  }

  // FC epilogue: h already f32
  #pragma unroll 1
  for (int m = 0; m < 16; ++m){
    float hv = hwp[m*HSTR2 + lane];
    float v = hv * wfc;
    #pragma unroll
    for (int off = 32; off >= 1; off >>= 1) v += __shfl_xor(v, off, 64);
    int n = n0 + m;
    if (lane == 0 && n < N) out[n] = v + bfc;
  }
}

extern "C" void kernel_launch(void* const* d_in, const int* in_sizes, int n_in,
                              void* d_out, int out_size, void* d_ws, size_t ws_size,
                              hipStream_t stream){
  const float* x     = (const float*)d_in[0];
  const int*   ei    = (const int*)d_in[1];
  const float* W_gcn = (const float*)d_in[2];
  const float* b_gcn = (const float*)d_in[3];
  const float* W_ih  = (const float*)d_in[4];
  const float* W_hh  = (const float*)d_in[5];
  const float* b_ih  = (const float*)d_in[6];
  const float* b_hh  = (const float*)d_in[7];
  const float* W_fc  = (const float*)d_in[8];
  const float* b_fc  = (const float*)d_in[9];
  float* out = (float*)d_out;
  const int N = in_sizes[0] / (T_STEPS*2);
  const int E = in_sizes[1] / 2;
  const int NBKT = (N + 63) >> 6;                 // 782 buckets of 64 nodes
  const int FLAT = NBKT * GRID_P;                 // 200192 table cells
  const int NB1024 = (FLAT + 1023) / 1024;        // 196 scan blocks (<=256)

  char* p = (char*)d_ws;
  auto alloc = [&](size_t bytes)->char*{
    char* r = p; p += (bytes + 255) & ~(size_t)255; return r;
  };
  int*      table     = (int*)     alloc((size_t)FLAT*4);
  int*      part      = (int*)     alloc((size_t)FLAT*4);
  int*      bsum      = (int*)     alloc((size_t)NB1024*4);
  unsigned* sorted    = (unsigned*)alloc((size_t)E*4);
  int*      row_start = (int*)     alloc((size_t)(N+1)*4);
  int*      csr       = (int*)     alloc((size_t)E*4);
  float*    dinv      = (float*)   alloc((size_t)N*4);
  float*    rin       = (float*)   alloc((size_t)N*24*4);
  float*    xs        = (float*)   alloc((size_t)N*24*4);
  unsigned short* Bpk = (unsigned short*)alloc((size_t)24576*2);

  histA_packB_kernel<<<GRID_P, ABLK, 0, stream>>>(ei, E, NBKT, table, W_ih, W_hh, Bpk);
  scan1_kernel<<<NB1024, 1024, 0, stream>>>(table, part, bsum, FLAT);
  scatterC_kernel<<<GRID_P, ABLK, 0, stream>>>(ei, E, NBKT, table, part, bsum, NB1024, sorted);
  fineD_kernel<<<NBKT, 256, 0, stream>>>(sorted, part, bsum, NB1024, row_start, dinv, csr,
                                         x, (float4*)xs, N, NBKT);
  gather6_kernel<<<(N*12+255)/256, 256, 0, stream>>>((const float4*)xs, row_start, csr,
                                                     dinv, (float4*)rin, N);

  (void)hipFuncSetAttribute((const void*)gru16_kernel,
                            hipFuncAttributeMaxDynamicSharedMemorySize, LDS_TOTAL);
  int ntiles = (N + 15) / 16;                      // 3125
  int blocks = (ntiles + GWPB - 1) / GWPB;         // 241
  gru16_kernel<<<blocks, GBLOCK, LDS_TOTAL, stream>>>(rin, W_gcn, b_gcn, Bpk,
                                                      b_ih, b_hh, W_fc, b_fc,
                                                      out, N, ntiles);
}